// Round 8
// baseline (231.244 us; speedup 1.0000x reference)
//
#include <hip/hip_runtime.h>
#include <hip/hip_bf16.h>

// Problem constants (SelectSphereConv, graph level 6)
#define VN 40962
#define NG 10241          // groups of 4 vertices, one per block
#define LDA_B 1168        // A-tile row stride bytes (576*2 + 16 pad)
#define LDS_TOT 18688     // 16 rows x 1168; C staging reuses this region
#define XT_BYTES (VN * 512)

typedef float f32x4 __attribute__((ext_vector_type(4)));
typedef float f32x2 __attribute__((ext_vector_type(2)));
typedef __bf16 bf16x8 __attribute__((ext_vector_type(8)));

__device__ __forceinline__ float bf16lo(unsigned u) {
    return __builtin_bit_cast(float, u << 16);
}
__device__ __forceinline__ float bf16hi(unsigned u) {
    return __builtin_bit_cast(float, u & 0xffff0000u);
}
__device__ __forceinline__ unsigned bf16b(float x) {
    __bf16 h = (__bf16)x;
    return (unsigned)__builtin_bit_cast(unsigned short, h);
}

// ---------------------------------------------------------------------------
// Kernel 1: transpose x [256(t=b*64+c), V] f32 -> x_t [V, 256] bf16
// ---------------------------------------------------------------------------
__global__ __launch_bounds__(256) void k_transpose(const float* __restrict__ x,
                                                   __bf16* __restrict__ xt) {
    __shared__ __bf16 tile[64][65];
    const int v0 = blockIdx.x * 64;
    const int t0 = blockIdx.y * 64;
    const int lane = threadIdx.x & 63;
    const int sub = threadIdx.x >> 6;

#pragma unroll
    for (int r = 0; r < 16; ++r) {
        const int t = t0 + r * 4 + sub;
        const int v = v0 + lane;
        float val = (v < VN) ? x[(size_t)t * VN + v] : 0.f;   // coalesced
        tile[r * 4 + sub][lane] = (__bf16)val;
    }
    __syncthreads();
#pragma unroll
    for (int r = 0; r < 16; ++r) {
        const int vv = r * 4 + sub;
        const int v = v0 + vv;
        if (v < VN) xt[(size_t)v * 256 + t0 + lane] = tile[lane][vv];  // coalesced
    }
}

// ---------------------------------------------------------------------------
// Kernel 2: pre-swizzle conv_w into 16x16x32 B-fragment order (R1-validated):
//   wf[((w*18+ks)*64 + lane)*8 + e] = conv_w[(w*16+(lane&15))*576
//                                            + ks*32 + (lane>>4)*8 + e]
// ---------------------------------------------------------------------------
__global__ __launch_bounds__(64) void k_wprep(const float* __restrict__ conv_w,
                                              __bf16* __restrict__ wf) {
    const int id = blockIdx.x;           // w*18 + ks, 0..71
    const int ks = id % 18;
    const int w  = id / 18;
    const int lane = threadIdx.x;        // 0..63
    const int o  = w * 16 + (lane & 15);
    const int kb = (lane >> 4) * 8;
    const float* wrow = conv_w + (size_t)o * 576 + ks * 32 + kb;
    bf16x8 f;
#pragma unroll
    for (int e = 0; e < 8; ++e) f[e] = (__bf16)wrow[e];
    *(bf16x8*)(wf + ((size_t)id * 64 + lane) * 8) = f;
}

// ---------------------------------------------------------------------------
// Kernel 3: fused gather + interpolate + conv. ONE group (4 vertices) per
//   block; LDS = 18688 B (C staging reuses the A-tile region after barrier 2)
//   -> 8 blocks/CU = 100% occupancy target; __launch_bounds__(256,8) caps
//   VGPR at 64. W-fragments streamed from wf (L2-resident) to stay under the
//   VGPR cap. Phase-1 remap: thread = (c-pair p, batch bb, vertex-half vh);
//   dword gathers (wave = 256B contiguous per neighbor row) and contiguous
//   conflict-free 36B LDS writes. 3 barriers.
// ---------------------------------------------------------------------------
__global__ __launch_bounds__(256, 8) void k_fused(const __bf16* __restrict__ xt,
                                                  const int* __restrict__ index,
                                                  const float* __restrict__ itp_mat,
                                                  const __bf16* __restrict__ wf,
                                                  const float* __restrict__ conv_b,
                                                  float* __restrict__ out) {
    __shared__ char smem[LDS_TOT];

    const int tid  = threadIdx.x;
    const int lane = tid & 63;
    const int w    = tid >> 6;
    const int l16  = lane & 15;
    const int g4   = lane >> 4;
    const int v0   = blockIdx.x * 4;

    // phase-1 mapping: p = c-pair (c = 2p, 2p+1), bb = batch, vh = vertex half
    const int p  = tid & 31;
    const int bb = (tid >> 5) & 3;
    const int vh = tid >> 7;

    // ---------------- phase 1: gather + interpolate ----------------
#pragma unroll
    for (int vs = 0; vs < 2; ++vs) {
        const int vv = vh + 2 * vs;               // wave-uniform
        const int v  = v0 + vv;
        const int vm = (v < VN) ? v : VN - 1;     // clamp tail
        const int* idxv = index + (size_t)vm * 9;       // uniform -> s_load
        const float* am = itp_mat + (size_t)vm * 81;    // uniform -> s_load

        unsigned gd[9];
#pragma unroll
        for (int k = 0; k < 9; ++k)
            gd[k] = *(const unsigned*)(xt + (size_t)idxv[k] * 256 + bb * 64 + 2 * p);

        float s0[9], s1[9];
#pragma unroll
        for (int j = 0; j < 9; ++j) { s0[j] = 0.f; s1[j] = 0.f; }
#pragma unroll
        for (int k = 0; k < 9; ++k) {
            const float glo = bf16lo(gd[k]);      // channel 2p
            const float ghi = bf16hi(gd[k]);      // channel 2p+1
#pragma unroll
            for (int j = 0; j < 9; ++j) {
                const float a = am[k * 9 + j];
                s0[j] += glo * a;
                s1[j] += ghi * a;
            }
        }

        // pack 18 bf16 -> 9 dwords; contiguous 36B at row (vv*4+bb), col 36p.
        // banks 9p (+4 for other half-wave) mod 32: conflict-free / 2-way.
        unsigned* wp = (unsigned*)(smem + (size_t)(vv * 4 + bb) * LDA_B + 36 * p);
#pragma unroll
        for (int q = 0; q < 9; ++q) {
            const int t0i = 2 * q, t1i = 2 * q + 1;
            const float e0 = (t0i < 9) ? s0[t0i] : s1[t0i - 9];
            const float e1 = (t1i < 9) ? s0[t1i] : s1[t1i - 9];
            wp[q] = bf16b(e0) | (bf16b(e1) << 16);
        }
    }
    __syncthreads();   // (1) A-tile ready

    // ---------------- phase 2: MFMA (A = itp tile, B = streamed W) --------
    f32x4 acc = {0.f, 0.f, 0.f, 0.f};
    {
        const char* ar = smem + l16 * LDA_B + g4 * 16;
        const __bf16* wfp = wf + ((size_t)(w * 18) * 64 + lane) * 8;
#pragma unroll
        for (int ks = 0; ks < 18; ++ks) {
            bf16x8 a  = *(const bf16x8*)(ar + ks * 64);
            bf16x8 wb = *(const bf16x8*)(wfp + (size_t)ks * 512);
            acc = __builtin_amdgcn_mfma_f32_16x16x32_bf16(a, wb, acc, 0, 0, 0);
        }
    }
    __syncthreads();   // (2) all A-tile reads done -> region reusable for C

    // ---------------- C staging (reuses A region) ----------------
    {
        float* c_lds = (float*)smem;   // [16][68] f32 = 4352 B
#pragma unroll
        for (int r = 0; r < 4; ++r)
            c_lds[(g4 * 4 + r) * 68 + w * 16 + l16] = acc[r];
    }
    __syncthreads();   // (3) C ready

    // ---------------- epilogue: thread (b = w, o = lane) ----------------
    {
        const float* c_lds = (const float*)smem;
        const float bias_v = conv_b[lane];
        float vals[4];
#pragma unroll
        for (int vv = 0; vv < 4; ++vv)
            vals[vv] = c_lds[(vv * 4 + w) * 68 + lane] + bias_v;
        float* op = out + (size_t)tid * VN + v0;   // out[(b*64+o)*V + v]
        const int vleft = VN - v0;
        if (vleft >= 4) {
            *(f32x2*)op       = f32x2{vals[0], vals[1]};
            *(f32x2*)(op + 2) = f32x2{vals[2], vals[3]};
        } else {
#pragma unroll
            for (int vv = 0; vv < 4; ++vv) if (vv < vleft) op[vv] = vals[vv];
        }
    }
}

// ---------------------------------------------------------------------------
extern "C" void kernel_launch(void* const* d_in, const int* in_sizes, int n_in,
                              void* d_out, int out_size, void* d_ws, size_t ws_size,
                              hipStream_t stream) {
    const float* x       = (const float*)d_in[0];
    const int*   index   = (const int*)d_in[1];
    const float* itp_mat = (const float*)d_in[2];
    const float* conv_w  = (const float*)d_in[3];
    const float* conv_b  = (const float*)d_in[4];
    float* out = (float*)d_out;

    __bf16* xt = (__bf16*)d_ws;                          // 20,972,544 B
    __bf16* wfrag = (__bf16*)((char*)d_ws + XT_BYTES);   // + 73,728 B

    dim3 tgrid((VN + 63) / 64, 4, 1);
    k_transpose<<<tgrid, 256, 0, stream>>>(x, xt);
    k_wprep<<<72, 64, 0, stream>>>(conv_w, wfrag);
    k_fused<<<NG, 256, 0, stream>>>(xt, index, itp_mat, wfrag, conv_b, out);
}

// Round 9
// 159.180 us; speedup vs baseline: 1.4527x; 1.4527x over previous
//
#include <hip/hip_runtime.h>
#include <hip/hip_bf16.h>

// Problem constants (SelectSphereConv, graph level 6)
#define VN 40962
#define NG 10241          // groups of 4 vertices, one per block
#define LDA_B 1168        // A-tile row stride bytes (576*2 + 16 pad)
#define LDS_TOT 18688     // 16 rows x 1168; C staging reuses this region
#define XT_BYTES (VN * 512)

typedef float f32x4 __attribute__((ext_vector_type(4)));
typedef float f32x2 __attribute__((ext_vector_type(2)));
typedef __bf16 bf16x8 __attribute__((ext_vector_type(8)));

__device__ __forceinline__ float bf16lo(unsigned u) {
    return __builtin_bit_cast(float, u << 16);
}
__device__ __forceinline__ float bf16hi(unsigned u) {
    return __builtin_bit_cast(float, u & 0xffff0000u);
}
__device__ __forceinline__ unsigned bf16b(float x) {
    __bf16 h = (__bf16)x;
    return (unsigned)__builtin_bit_cast(unsigned short, h);
}

// ---------------------------------------------------------------------------
// Kernel 1: transpose x [256(t=b*64+c), V] f32 -> x_t [V, 256] bf16
// ---------------------------------------------------------------------------
__global__ __launch_bounds__(256) void k_transpose(const float* __restrict__ x,
                                                   __bf16* __restrict__ xt) {
    __shared__ __bf16 tile[64][65];
    const int v0 = blockIdx.x * 64;
    const int t0 = blockIdx.y * 64;
    const int lane = threadIdx.x & 63;
    const int sub = threadIdx.x >> 6;

#pragma unroll
    for (int r = 0; r < 16; ++r) {
        const int t = t0 + r * 4 + sub;
        const int v = v0 + lane;
        float val = (v < VN) ? x[(size_t)t * VN + v] : 0.f;   // coalesced
        tile[r * 4 + sub][lane] = (__bf16)val;
    }
    __syncthreads();
#pragma unroll
    for (int r = 0; r < 16; ++r) {
        const int vv = r * 4 + sub;
        const int v = v0 + vv;
        if (v < VN) xt[(size_t)v * 256 + t0 + lane] = tile[lane][vv];  // coalesced
    }
}

// ---------------------------------------------------------------------------
// Kernel 2: pre-swizzle conv_w into 16x16x32 B-fragment order (R1-validated):
//   wf[((w*18+ks)*64 + lane)*8 + e] = conv_w[(w*16+(lane&15))*576
//                                            + ks*32 + (lane>>4)*8 + e]
// ---------------------------------------------------------------------------
__global__ __launch_bounds__(64) void k_wprep(const float* __restrict__ conv_w,
                                              __bf16* __restrict__ wf) {
    const int id = blockIdx.x;           // w*18 + ks, 0..71
    const int ks = id % 18;
    const int w  = id / 18;
    const int lane = threadIdx.x;        // 0..63
    const int o  = w * 16 + (lane & 15);
    const int kb = (lane >> 4) * 8;
    const float* wrow = conv_w + (size_t)o * 576 + ks * 32 + kb;
    bf16x8 f;
#pragma unroll
    for (int e = 0; e < 8; ++e) f[e] = (__bf16)wrow[e];
    *(bf16x8*)(wf + ((size_t)id * 64 + lane) * 8) = f;
}

// ---------------------------------------------------------------------------
// Kernel 3: fused gather + interpolate + conv. ONE group (4 vertices) per
//   block; LDS = 18688 B (C staging reuses the A-tile region after barrier 2)
//   -> LDS cap 8 blocks/CU. __launch_bounds__(256,6): VGPR budget ~85 --
//   enough for phase-1's ~27 live data regs WITHOUT spilling (R8's (256,8)
//   forced VGPR=32 -> 870MB scratch traffic, 3x regression); if natural
//   allocation lands <=64 the HW still schedules all 8 blocks.
//   W-fragments streamed from wf (L2-resident). Phase-1: thread =
//   (c-pair p, batch bb, vertex-half vh); dword gathers (256B/wave/neighbor)
//   and contiguous conflict-free 36B LDS writes. 3 barriers.
// ---------------------------------------------------------------------------
__global__ __launch_bounds__(256, 6) void k_fused(const __bf16* __restrict__ xt,
                                                  const int* __restrict__ index,
                                                  const float* __restrict__ itp_mat,
                                                  const __bf16* __restrict__ wf,
                                                  const float* __restrict__ conv_b,
                                                  float* __restrict__ out) {
    __shared__ char smem[LDS_TOT];

    const int tid  = threadIdx.x;
    const int lane = tid & 63;
    const int w    = tid >> 6;
    const int l16  = lane & 15;
    const int g4   = lane >> 4;
    const int v0   = blockIdx.x * 4;

    // phase-1 mapping: p = c-pair (c = 2p, 2p+1), bb = batch, vh = vertex half
    const int p  = tid & 31;
    const int bb = (tid >> 5) & 3;
    const int vh = tid >> 7;

    // ---------------- phase 1: gather + interpolate ----------------
#pragma unroll
    for (int vs = 0; vs < 2; ++vs) {
        const int vv = vh + 2 * vs;               // wave-uniform
        const int v  = v0 + vv;
        const int vm = (v < VN) ? v : VN - 1;     // clamp tail
        const int* idxv = index + (size_t)vm * 9;       // uniform -> s_load
        const float* am = itp_mat + (size_t)vm * 81;    // uniform -> s_load

        unsigned gd[9];
#pragma unroll
        for (int k = 0; k < 9; ++k)
            gd[k] = *(const unsigned*)(xt + (size_t)idxv[k] * 256 + bb * 64 + 2 * p);

        float s0[9], s1[9];
#pragma unroll
        for (int j = 0; j < 9; ++j) { s0[j] = 0.f; s1[j] = 0.f; }
#pragma unroll
        for (int k = 0; k < 9; ++k) {
            const float glo = bf16lo(gd[k]);      // channel 2p
            const float ghi = bf16hi(gd[k]);      // channel 2p+1
#pragma unroll
            for (int j = 0; j < 9; ++j) {
                const float a = am[k * 9 + j];
                s0[j] += glo * a;
                s1[j] += ghi * a;
            }
        }

        // pack 18 bf16 -> 9 dwords; contiguous 36B at row (vv*4+bb), col 36p.
        // banks 9p (+4 for other half-wave) mod 32: conflict-free / 2-way.
        unsigned* wp = (unsigned*)(smem + (size_t)(vv * 4 + bb) * LDA_B + 36 * p);
#pragma unroll
        for (int q = 0; q < 9; ++q) {
            const int t0i = 2 * q, t1i = 2 * q + 1;
            const float e0 = (t0i < 9) ? s0[t0i] : s1[t0i - 9];
            const float e1 = (t1i < 9) ? s0[t1i] : s1[t1i - 9];
            wp[q] = bf16b(e0) | (bf16b(e1) << 16);
        }
    }
    __syncthreads();   // (1) A-tile ready

    // ---------------- phase 2: MFMA (A = itp tile, B = streamed W) --------
    f32x4 acc = {0.f, 0.f, 0.f, 0.f};
    {
        const char* ar = smem + l16 * LDA_B + g4 * 16;
        const __bf16* wfp = wf + ((size_t)(w * 18) * 64 + lane) * 8;
#pragma unroll
        for (int ks = 0; ks < 18; ++ks) {
            bf16x8 a  = *(const bf16x8*)(ar + ks * 64);
            bf16x8 wb = *(const bf16x8*)(wfp + (size_t)ks * 512);
            acc = __builtin_amdgcn_mfma_f32_16x16x32_bf16(a, wb, acc, 0, 0, 0);
        }
    }
    __syncthreads();   // (2) all A-tile reads done -> region reusable for C

    // ---------------- C staging (reuses A region) ----------------
    {
        float* c_lds = (float*)smem;   // [16][68] f32 = 4352 B
#pragma unroll
        for (int r = 0; r < 4; ++r)
            c_lds[(g4 * 4 + r) * 68 + w * 16 + l16] = acc[r];
    }
    __syncthreads();   // (3) C ready

    // ---------------- epilogue: thread (b = w, o = lane) ----------------
    {
        const float* c_lds = (const float*)smem;
        const float bias_v = conv_b[lane];
        float vals[4];
#pragma unroll
        for (int vv = 0; vv < 4; ++vv)
            vals[vv] = c_lds[(vv * 4 + w) * 68 + lane] + bias_v;
        float* op = out + (size_t)tid * VN + v0;   // out[(b*64+o)*V + v]
        const int vleft = VN - v0;
        if (vleft >= 4) {
            *(f32x2*)op       = f32x2{vals[0], vals[1]};
            *(f32x2*)(op + 2) = f32x2{vals[2], vals[3]};
        } else {
#pragma unroll
            for (int vv = 0; vv < 4; ++vv) if (vv < vleft) op[vv] = vals[vv];
        }
    }
}

// ---------------------------------------------------------------------------
extern "C" void kernel_launch(void* const* d_in, const int* in_sizes, int n_in,
                              void* d_out, int out_size, void* d_ws, size_t ws_size,
                              hipStream_t stream) {
    const float* x       = (const float*)d_in[0];
    const int*   index   = (const int*)d_in[1];
    const float* itp_mat = (const float*)d_in[2];
    const float* conv_w  = (const float*)d_in[3];
    const float* conv_b  = (const float*)d_in[4];
    float* out = (float*)d_out;

    __bf16* xt = (__bf16*)d_ws;                          // 20,972,544 B
    __bf16* wfrag = (__bf16*)((char*)d_ws + XT_BYTES);   // + 73,728 B

    dim3 tgrid((VN + 63) / 64, 4, 1);
    k_transpose<<<tgrid, 256, 0, stream>>>(x, xt);
    k_wprep<<<72, 64, 0, stream>>>(conv_w, wfrag);
    k_fused<<<NG, 256, 0, stream>>>(xt, index, itp_mat, wfrag, conv_b, out);
}

// Round 10
// 121.275 us; speedup vs baseline: 1.9068x; 1.3126x over previous
//
#include <hip/hip_runtime.h>
#include <hip/hip_bf16.h>

// Problem constants (SelectSphereConv, graph level 6)
#define VN 40962
#define NG 10241          // groups of 4 vertices, one per block
#define LDA_B 1168        // A-tile row stride bytes (576*2 + 16 pad)
#define LDS_TOT 18688     // 16 rows x 1168; C staging reuses this region
#define XT_BYTES (VN * 512)

typedef float f32x4 __attribute__((ext_vector_type(4)));
typedef float f32x2 __attribute__((ext_vector_type(2)));
typedef __bf16 bf16x8 __attribute__((ext_vector_type(8)));

__device__ __forceinline__ float bf16lo(unsigned u) {
    return __builtin_bit_cast(float, u << 16);
}
__device__ __forceinline__ float bf16hi(unsigned u) {
    return __builtin_bit_cast(float, u & 0xffff0000u);
}
__device__ __forceinline__ unsigned bf16b(float x) {
    __bf16 h = (__bf16)x;
    return (unsigned)__builtin_bit_cast(unsigned short, h);
}

// ---------------------------------------------------------------------------
// Kernel 1: transpose x [256(t=b*64+c), V] f32 -> x_t [V, 256] bf16
// ---------------------------------------------------------------------------
__global__ __launch_bounds__(256) void k_transpose(const float* __restrict__ x,
                                                   __bf16* __restrict__ xt) {
    __shared__ __bf16 tile[64][65];
    const int v0 = blockIdx.x * 64;
    const int t0 = blockIdx.y * 64;
    const int lane = threadIdx.x & 63;
    const int sub = threadIdx.x >> 6;

#pragma unroll
    for (int r = 0; r < 16; ++r) {
        const int t = t0 + r * 4 + sub;
        const int v = v0 + lane;
        float val = (v < VN) ? x[(size_t)t * VN + v] : 0.f;   // coalesced
        tile[r * 4 + sub][lane] = (__bf16)val;
    }
    __syncthreads();
#pragma unroll
    for (int r = 0; r < 16; ++r) {
        const int vv = r * 4 + sub;
        const int v = v0 + vv;
        if (v < VN) xt[(size_t)v * 256 + t0 + lane] = tile[lane][vv];  // coalesced
    }
}

// ---------------------------------------------------------------------------
// Kernel 2: pre-swizzle conv_w into 16x16x32 B-fragment order (R1-validated):
//   wf[((w*18+ks)*64 + lane)*8 + e] = conv_w[(w*16+(lane&15))*576
//                                            + ks*32 + (lane>>4)*8 + e]
// ---------------------------------------------------------------------------
__global__ __launch_bounds__(64) void k_wprep(const float* __restrict__ conv_w,
                                              __bf16* __restrict__ wf) {
    const int id = blockIdx.x;           // w*18 + ks, 0..71
    const int ks = id % 18;
    const int w  = id / 18;
    const int lane = threadIdx.x;        // 0..63
    const int o  = w * 16 + (lane & 15);
    const int kb = (lane >> 4) * 8;
    const float* wrow = conv_w + (size_t)o * 576 + ks * 32 + kb;
    bf16x8 f;
#pragma unroll
    for (int e = 0; e < 8; ++e) f[e] = (__bf16)wrow[e];
    *(bf16x8*)(wf + ((size_t)id * 64 + lane) * 8) = f;
}

// ---------------------------------------------------------------------------
// Kernel 3: fused gather + interpolate + conv. ONE group (4 vertices) per
//   block; LDS = 18688 B (C staging reuses A-tile region after barrier 2)
//   -> LDS caps at 8 blocks/CU. NO waves-per-EU hint: R8 (,8)->VGPR32 and
//   R9 (,6)->VGPR40 both forced spills (+275..870MB scratch traffic); R7's
//   unhinted build chose 36 VGPR spill-free at 70% occupancy. Let the
//   allocator breathe. W-fragments streamed from wf (L2-resident).
//   Phase-1: thread = (c-pair p, batch bb, vertex-half vh); dword gathers
//   (256B/wave/neighbor) and contiguous conflict-free 36B LDS writes.
// ---------------------------------------------------------------------------
__global__ __launch_bounds__(256) void k_fused(const __bf16* __restrict__ xt,
                                               const int* __restrict__ index,
                                               const float* __restrict__ itp_mat,
                                               const __bf16* __restrict__ wf,
                                               const float* __restrict__ conv_b,
                                               float* __restrict__ out) {
    __shared__ char smem[LDS_TOT];

    const int tid  = threadIdx.x;
    const int lane = tid & 63;
    const int w    = tid >> 6;
    const int l16  = lane & 15;
    const int g4   = lane >> 4;
    const int v0   = blockIdx.x * 4;

    // phase-1 mapping: p = c-pair (c = 2p, 2p+1), bb = batch, vh = vertex half
    const int p  = tid & 31;
    const int bb = (tid >> 5) & 3;
    const int vh = tid >> 7;

    // ---------------- phase 1: gather + interpolate ----------------
#pragma unroll
    for (int vs = 0; vs < 2; ++vs) {
        const int vv = vh + 2 * vs;               // wave-uniform
        const int v  = v0 + vv;
        const int vm = (v < VN) ? v : VN - 1;     // clamp tail
        const int* idxv = index + (size_t)vm * 9;       // uniform -> s_load
        const float* am = itp_mat + (size_t)vm * 81;    // uniform -> s_load

        unsigned gd[9];
#pragma unroll
        for (int k = 0; k < 9; ++k)
            gd[k] = *(const unsigned*)(xt + (size_t)idxv[k] * 256 + bb * 64 + 2 * p);

        float s0[9], s1[9];
#pragma unroll
        for (int j = 0; j < 9; ++j) { s0[j] = 0.f; s1[j] = 0.f; }
#pragma unroll
        for (int k = 0; k < 9; ++k) {
            const float glo = bf16lo(gd[k]);      // channel 2p
            const float ghi = bf16hi(gd[k]);      // channel 2p+1
#pragma unroll
            for (int j = 0; j < 9; ++j) {
                const float a = am[k * 9 + j];
                s0[j] += glo * a;
                s1[j] += ghi * a;
            }
        }

        // pack 18 bf16 -> 9 dwords; contiguous 36B at row (vv*4+bb), col 36p.
        // banks 9p (+4 for other half-wave) mod 32: conflict-free / 2-way.
        unsigned* wp = (unsigned*)(smem + (size_t)(vv * 4 + bb) * LDA_B + 36 * p);
#pragma unroll
        for (int q = 0; q < 9; ++q) {
            const int t0i = 2 * q, t1i = 2 * q + 1;
            const float e0 = (t0i < 9) ? s0[t0i] : s1[t0i - 9];
            const float e1 = (t1i < 9) ? s0[t1i] : s1[t1i - 9];
            wp[q] = bf16b(e0) | (bf16b(e1) << 16);
        }
    }
    __syncthreads();   // (1) A-tile ready

    // ---------------- phase 2: MFMA (A = itp tile, B = streamed W) --------
    f32x4 acc = {0.f, 0.f, 0.f, 0.f};
    {
        const char* ar = smem + l16 * LDA_B + g4 * 16;
        const __bf16* wfp = wf + ((size_t)(w * 18) * 64 + lane) * 8;
#pragma unroll
        for (int ks = 0; ks < 18; ++ks) {
            bf16x8 a  = *(const bf16x8*)(ar + ks * 64);
            bf16x8 wb = *(const bf16x8*)(wfp + (size_t)ks * 512);
            acc = __builtin_amdgcn_mfma_f32_16x16x32_bf16(a, wb, acc, 0, 0, 0);
        }
    }
    __syncthreads();   // (2) all A-tile reads done -> region reusable for C

    // ---------------- C staging (reuses A region) ----------------
    {
        float* c_lds = (float*)smem;   // [16][68] f32 = 4352 B
#pragma unroll
        for (int r = 0; r < 4; ++r)
            c_lds[(g4 * 4 + r) * 68 + w * 16 + l16] = acc[r];
    }
    __syncthreads();   // (3) C ready

    // ---------------- epilogue: thread (b = w, o = lane) ----------------
    {
        const float* c_lds = (const float*)smem;
        const float bias_v = conv_b[lane];
        float vals[4];
#pragma unroll
        for (int vv = 0; vv < 4; ++vv)
            vals[vv] = c_lds[(vv * 4 + w) * 68 + lane] + bias_v;
        float* op = out + (size_t)tid * VN + v0;   // out[(b*64+o)*V + v]
        const int vleft = VN - v0;
        if (vleft >= 4) {
            *(f32x2*)op       = f32x2{vals[0], vals[1]};
            *(f32x2*)(op + 2) = f32x2{vals[2], vals[3]};
        } else {
#pragma unroll
            for (int vv = 0; vv < 4; ++vv) if (vv < vleft) op[vv] = vals[vv];
        }
    }
}

// ---------------------------------------------------------------------------
extern "C" void kernel_launch(void* const* d_in, const int* in_sizes, int n_in,
                              void* d_out, int out_size, void* d_ws, size_t ws_size,
                              hipStream_t stream) {
    const float* x       = (const float*)d_in[0];
    const int*   index   = (const int*)d_in[1];
    const float* itp_mat = (const float*)d_in[2];
    const float* conv_w  = (const float*)d_in[3];
    const float* conv_b  = (const float*)d_in[4];
    float* out = (float*)d_out;

    __bf16* xt = (__bf16*)d_ws;                          // 20,972,544 B
    __bf16* wfrag = (__bf16*)((char*)d_ws + XT_BYTES);   // + 73,728 B

    dim3 tgrid((VN + 63) / 64, 4, 1);
    k_transpose<<<tgrid, 256, 0, stream>>>(x, xt);
    k_wprep<<<72, 64, 0, stream>>>(conv_w, wfrag);
    k_fused<<<NG, 256, 0, stream>>>(xt, index, itp_mat, wfrag, conv_b, out);
}

// Round 12
// 98.525 us; speedup vs baseline: 2.3471x; 1.2309x over previous
//
#include <hip/hip_runtime.h>
#include <hip/hip_bf16.h>

// Problem constants (SelectSphereConv, graph level 6)
#define VN 40962
#define NG 10241          // groups of 4 vertices, one per block
#define LDA_B 1168        // A-tile row stride bytes (576*2 + 16 pad)
#define LDS_TOT 18688     // 16 rows x 1168; C staging reuses this region
#define XT_BYTES (VN * 512)

typedef float f32x4 __attribute__((ext_vector_type(4)));
typedef float f32x2 __attribute__((ext_vector_type(2)));
typedef __bf16 bf16x8 __attribute__((ext_vector_type(8)));

// ---------------------------------------------------------------------------
// Kernel 1: transpose x [256(t=b*64+c), V] f32 -> x_t [V, 256] bf16
// ---------------------------------------------------------------------------
__global__ __launch_bounds__(256) void k_transpose(const float* __restrict__ x,
                                                   __bf16* __restrict__ xt) {
    __shared__ __bf16 tile[64][65];
    const int v0 = blockIdx.x * 64;
    const int t0 = blockIdx.y * 64;
    const int lane = threadIdx.x & 63;
    const int sub = threadIdx.x >> 6;

#pragma unroll
    for (int r = 0; r < 16; ++r) {
        const int t = t0 + r * 4 + sub;
        const int v = v0 + lane;
        float val = (v < VN) ? x[(size_t)t * VN + v] : 0.f;   // coalesced
        tile[r * 4 + sub][lane] = (__bf16)val;
    }
    __syncthreads();
#pragma unroll
    for (int r = 0; r < 16; ++r) {
        const int vv = r * 4 + sub;
        const int v = v0 + vv;
        if (v < VN) xt[(size_t)v * 256 + t0 + lane] = tile[lane][vv];  // coalesced
    }
}

// ---------------------------------------------------------------------------
// Kernel 2: pre-swizzle conv_w into 16x16x32 B-fragment order (R1-validated):
//   wf[((w*18+ks)*64 + lane)*8 + e] = conv_w[(w*16+(lane&15))*576
//                                            + ks*32 + (lane>>4)*8 + e]
// ---------------------------------------------------------------------------
__global__ __launch_bounds__(64) void k_wprep(const float* __restrict__ conv_w,
                                              __bf16* __restrict__ wf) {
    const int id = blockIdx.x;           // w*18 + ks, 0..71
    const int ks = id % 18;
    const int w  = id / 18;
    const int lane = threadIdx.x;        // 0..63
    const int o  = w * 16 + (lane & 15);
    const int kb = (lane >> 4) * 8;
    const float* wrow = conv_w + (size_t)o * 576 + ks * 32 + kb;
    bf16x8 f;
#pragma unroll
    for (int e = 0; e < 8; ++e) f[e] = (__bf16)wrow[e];
    *(bf16x8*)(wf + ((size_t)id * 64 + lane) * 8) = f;
}

// ---------------------------------------------------------------------------
// Kernel 3: fused gather + interpolate + conv. ONE group (4 vertices) per
//   block. R7 verbatim EXCEPT: C staging reuses the A-tile LDS region after
//   barrier 2 -> LDS 23040 -> 18688 B -> 8 blocks/CU (R7 was 6). Phase-1 is
//   the proven VGPR-minimal form (R7: 36 regs, no spill); NO waves-per-EU
//   hint (R8: (,8)->spill x3 regression; R9: (,6)->spill). Direct store from
//   accumulator is WRONG here (R11: C/D mapping is row=M=vv*4+b, col=N=o,
//   and the corrected scatter would be 4B/line) -- LDS staging IS the
//   transpose engine. 3 barriers.
// ---------------------------------------------------------------------------
__global__ __launch_bounds__(256) void k_fused(const __bf16* __restrict__ xt,
                                               const int* __restrict__ index,
                                               const float* __restrict__ itp_mat,
                                               const __bf16* __restrict__ wf,
                                               const float* __restrict__ conv_b,
                                               float* __restrict__ out) {
    __shared__ char smem[LDS_TOT];

    const int tid  = threadIdx.x;
    const int lane = tid & 63;
    const int w    = tid >> 6;      // batch b in phase 1 / epilogue; o-tile in MFMA
    const int l16  = lane & 15;
    const int g4   = lane >> 4;
    const int v0   = blockIdx.x * 4;

    // ---------------- phase 1: gather + interpolate (R7 verbatim) ----------
    // thread t = (b = w, c = lane); gathers xt[nb*256 + t] (2B, 128B/wave)
#pragma unroll 2
    for (int vv = 0; vv < 4; ++vv) {
        const int v  = v0 + vv;
        const int vm = (v < VN) ? v : VN - 1;           // clamp tail
        const int* idxv = index + (size_t)vm * 9;       // uniform -> s_load
        const float* am = itp_mat + (size_t)vm * 81;    // uniform -> s_load
        float gv[9];
#pragma unroll
        for (int k = 0; k < 9; ++k)
            gv[k] = (float)xt[(size_t)idxv[k] * 256 + tid];
        float s[9];
#pragma unroll
        for (int j = 0; j < 9; ++j) s[j] = 0.f;
#pragma unroll
        for (int k = 0; k < 9; ++k) {
            const float gk = gv[k];
#pragma unroll
            for (int j = 0; j < 9; ++j) s[j] += gk * am[k * 9 + j];
        }
        __bf16* rowp = (__bf16*)(smem + (vv * 4 + w) * LDA_B) + lane * 9;
#pragma unroll
        for (int j = 0; j < 9; ++j) rowp[j] = (__bf16)s[j];
    }
    __syncthreads();   // (1) A-tile ready

    // ---------------- phase 2: MFMA (A = itp tile, B = streamed W) --------
    f32x4 acc = {0.f, 0.f, 0.f, 0.f};
    {
        const char* ar = smem + l16 * LDA_B + g4 * 16;
        const __bf16* wfp = wf + ((size_t)(w * 18) * 64 + lane) * 8;
#pragma unroll
        for (int ks = 0; ks < 18; ++ks) {
            bf16x8 a  = *(const bf16x8*)(ar + ks * 64);
            bf16x8 wb = *(const bf16x8*)(wfp + (size_t)ks * 512);
            acc = __builtin_amdgcn_mfma_f32_16x16x32_bf16(a, wb, acc, 0, 0, 0);
        }
    }
    __syncthreads();   // (2) all A-tile reads done -> region reusable for C

    // ---------------- C staging (reuses A region; validated mapping) ------
    // D: reg-row (g4*4+r) = M = vv*4+b, col l16 = N = o-within-tile.
    {
        float* c_lds = (float*)smem;   // [16][68] f32 = 4352 B
#pragma unroll
        for (int r = 0; r < 4; ++r)
            c_lds[(g4 * 4 + r) * 68 + w * 16 + l16] = acc[r];
    }
    __syncthreads();   // (3) C ready

    // ---------------- epilogue: thread (b = w, o = lane) ----------------
    {
        const float* c_lds = (const float*)smem;
        const float bias_v = conv_b[lane];
        float vals[4];
#pragma unroll
        for (int vv = 0; vv < 4; ++vv)
            vals[vv] = c_lds[(vv * 4 + w) * 68 + lane] + bias_v;
        float* op = out + (size_t)tid * VN + v0;   // out[(b*64+o)*V + v]
        const int vleft = VN - v0;
        if (vleft >= 4) {
            *(f32x2*)op       = f32x2{vals[0], vals[1]};
            *(f32x2*)(op + 2) = f32x2{vals[2], vals[3]};
        } else {
#pragma unroll
            for (int vv = 0; vv < 4; ++vv) if (vv < vleft) op[vv] = vals[vv];
        }
    }
}

// ---------------------------------------------------------------------------
extern "C" void kernel_launch(void* const* d_in, const int* in_sizes, int n_in,
                              void* d_out, int out_size, void* d_ws, size_t ws_size,
                              hipStream_t stream) {
    const float* x       = (const float*)d_in[0];
    const int*   index   = (const int*)d_in[1];
    const float* itp_mat = (const float*)d_in[2];
    const float* conv_w  = (const float*)d_in[3];
    const float* conv_b  = (const float*)d_in[4];
    float* out = (float*)d_out;

    __bf16* xt = (__bf16*)d_ws;                          // 20,972,544 B
    __bf16* wfrag = (__bf16*)((char*)d_ws + XT_BYTES);   // + 73,728 B

    dim3 tgrid((VN + 63) / 64, 4, 1);
    k_transpose<<<tgrid, 256, 0, stream>>>(x, xt);
    k_wprep<<<72, 64, 0, stream>>>(conv_w, wfrag);
    k_fused<<<NG, 256, 0, stream>>>(xt, index, itp_mat, wfrag, conv_b, out);
}